// Round 6
// baseline (21100.169 us; speedup 1.0000x reference)
//
#include <hip/hip_runtime.h>

typedef short short8 __attribute__((ext_vector_type(8)));
typedef float f32x4 __attribute__((ext_vector_type(4)));
typedef unsigned short u16;
typedef unsigned long long u64;

#define NBLK 256
#define BDIM 512
#define BB 64
#define TT 512
#define II 512
#define HH 1024
#define NCLS 1000
#define HBUF (BB*HH)

__device__ __forceinline__ u16 f2bf(float f) {
  union { float f; unsigned u; } v; v.f = f;
  unsigned u = v.u;
  u += 0x7fffu + ((u >> 16) & 1u);   // RNE
  return (u16)(u >> 16);
}

__device__ __forceinline__ short8 cvt8(f32x4 a, f32x4 b) {
  short8 v;
  v[0] = (short)f2bf(a[0]); v[1] = (short)f2bf(a[1]);
  v[2] = (short)f2bf(a[2]); v[3] = (short)f2bf(a[3]);
  v[4] = (short)f2bf(b[0]); v[5] = (short)f2bf(b[1]);
  v[6] = (short)f2bf(b[2]); v[7] = (short)f2bf(b[3]);
  return v;
}

// Device-coherent 16B load of h (bypasses non-coherent L1/L2, served at LLC).
__device__ __forceinline__ short8 load_h16(const u16* p) {
  u64 a = __hip_atomic_load((const u64*)p,     __ATOMIC_RELAXED, __HIP_MEMORY_SCOPE_AGENT);
  u64 b = __hip_atomic_load((const u64*)p + 1, __ATOMIC_RELAXED, __HIP_MEMORY_SCOPE_AGENT);
  union { u64 q[2]; short8 v; } u; u.q[0] = a; u.q[1] = b; return u.v;
}

__device__ __forceinline__ unsigned ld_rlx(const unsigned* p) {
  return __hip_atomic_load(p, __ATOMIC_RELAXED, __HIP_MEMORY_SCOPE_AGENT);
}
__device__ __forceinline__ void st_rlx(unsigned* p, unsigned v) {
  __hip_atomic_store(p, v, __ATOMIC_RELAXED, __HIP_MEMORY_SCOPE_AGENT);
}

// x f32 -> bf16 pre-pass (tier A)
__global__ void cvt_x(const float* __restrict__ x, u16* __restrict__ xb, int n8) {
  int i = blockIdx.x * blockDim.x + threadIdx.x;
  const int stride = gridDim.x * blockDim.x;
  for (; i < n8; i += stride) {
    f32x4 a = ((const f32x4*)x)[2 * i];
    f32x4 b = ((const f32x4*)x)[2 * i + 1];
    ((short8*)xb)[i] = cvt8(a, b);
  }
}

// Decoupled persistent 2-layer LSTM. Blocks [0,128)=L0, [128,256)=L1.
// L0 barrier-A among 128 L0 blocks; its release word relA doubles as the
// producer flag L1 polls. L1 barrier-B among 128 L1 blocks; relB doubles as
// the consumer flag for L0's h0-ring flow control (depth 3 -> L0 runs <=2 ahead).
template<bool XBF>
__global__ __launch_bounds__(BDIM, 2) void lstm2_fused(
    const float* __restrict__ x, const u16* __restrict__ xb,
    const float* __restrict__ Wih0, const float* __restrict__ Whh0,
    const float* __restrict__ bih0, const float* __restrict__ bhh0,
    const float* __restrict__ Wih1, const float* __restrict__ Whh1,
    const float* __restrict__ bih1, const float* __restrict__ bhh1,
    u16* __restrict__ ring,          // 3 x [64][1024] bf16 (h0)
    u16* __restrict__ h1buf,         // 2 x [64][1024] bf16 (h1)
    float* __restrict__ h1f,
    unsigned* __restrict__ bar)
{
  __shared__ u16 wlds[32 * 2048];        // 128 KB (L1 row = 2048 elems; L0 uses 1536)
  __shared__ float gbuf[64][33];         // 8.4 KB gate staging (padded)
  __shared__ float blds[32];             // fused biases

  const bool isL1 = (blockIdx.x >= 128);
  const int wgl = isL1 ? (int)blockIdx.x - 128 : (int)blockIdx.x;
  const int j0 = wgl * 8;                // first hidden unit owned
  const int KX = isL1 ? HH : II;         // input-section K
  const int RL = KX + HH;                // total K per row: 2048 / 1536
  const int ROWB = RL * 2;               // row bytes in LDS (bf16)
  const float* Wih = isL1 ? Wih1 : Wih0;
  const float* Whh = isL1 ? Whh1 : Whh0;

  // ---- stage weights into LDS (f32 -> bf16), swizzle byte ^= (row&7)<<4 ----
  {
    const int cpr = RL / 8;
    for (int idx = threadIdx.x; idx < 32 * cpr; idx += BDIM) {
      int n = idx / cpr, cb = idx - n * cpr;
      int r = ((n >> 3) << 10) + j0 + (n & 7);   // global gate row: gate*1024 + j
      int k = cb * 8;
      const float* src = (k < KX) ? (Wih + (size_t)r * KX + k)
                                  : (Whh + (size_t)r * HH + (k - KX));
      f32x4 a = *(const f32x4*)src;
      f32x4 b = *(const f32x4*)(src + 4);
      short8 v = cvt8(a, b);
      unsigned byte = (unsigned)(n * ROWB + k * 2) ^ ((unsigned)(n & 7) << 4);
      *(short8*)((char*)wlds + byte) = v;
    }
    if (threadIdx.x < 32) {
      int n = threadIdx.x;
      int r = ((n >> 3) << 10) + j0 + (n & 7);
      blds[n] = (isL1 ? bih1[r] : bih0[r]) + (isL1 ? bhh1[r] : bhh0[r]);
    }
  }
  __syncthreads();

  const int lane = threadIdx.x & 63;
  const int wid = threadIdx.x >> 6;      // 8 waves
  const int mt = wid & 3, kg = wid >> 2; // 4 M-tiles x 2 K-halves
  const int m0 = mt << 4;
  const int row_a = m0 + (lane & 15);    // batch row for A fragments
  const int koff = (lane >> 4) << 3;     // k sub-offset per A/B layout
  const unsigned mask = (unsigned)(lane & 7) << 4;
  const unsigned nb0 = (unsigned)((lane & 15) * ROWB);
  const unsigned nb1 = nb0 + (unsigned)(16 * ROWB);
  const char* wch = (const char*)wlds;

  const int tb = threadIdx.x >> 3, tj = threadIdx.x & 7;  // update-phase (batch, unit)

  const int nsteps = RL >> 5;            // 48 / 64 k-steps of 32
  const int half = nsteps >> 1;
  const int ks_begin = kg * half, ks_end = ks_begin + half;
  const int bstep = KX >> 5;             // input-region / recurrent-region boundary
  const int r1e = (ks_end < bstep) ? ks_end : bstep;
  const int r2b = (ks_begin > bstep) ? ks_begin : bstep;

  unsigned* const arrA = bar;           // L0 arrive
  unsigned* const relA = bar + 64;      // L0 release / producer flag
  unsigned* const arrB = bar + 256;     // L1 arrive
  unsigned* const relB = bar + 320;     // L1 release / consumer flag

  float c_state = 0.f;

  // coherent-h K-loop helper (recurrent/input sections reading h at LLC)
  auto kloop_h = [&](const u16* base, int kadj, int ks0, int ks1,
                     f32x4& a0, f32x4& a1) {
#pragma unroll
    for (int ks = ks0; ks < ks1; ++ks) {
      int kk = (ks << 5) + koff;
      short8 av = load_h16(base + (kk - kadj));
      unsigned o = (unsigned)(kk * 2) ^ mask;
      short8 bv0 = *(const short8*)(wch + (nb0 + o));
      short8 bv1 = *(const short8*)(wch + (nb1 + o));
      a0 = __builtin_amdgcn_mfma_f32_16x16x32_bf16(av, bv0, a0, 0, 0, 0);
      a1 = __builtin_amdgcn_mfma_f32_16x16x32_bf16(av, bv1, a1, 0, 0, 0);
    }
  };

  // partial-combine + nonlinearity + state update + packed coherent h store
  auto step_tail = [&](f32x4 acc0, f32x4 acc1, u16* hout, bool wf) {
    const int colA = lane & 15;
    const int rowD = m0 + ((lane >> 4) << 2);
    if (kg == 1) {
#pragma unroll
      for (int r = 0; r < 4; ++r) {
        gbuf[rowD + r][colA] = acc0[r];
        gbuf[rowD + r][colA + 16] = acc1[r];
      }
    }
    __syncthreads();
    if (kg == 0) {
#pragma unroll
      for (int r = 0; r < 4; ++r) {
        gbuf[rowD + r][colA] += acc0[r];
        gbuf[rowD + r][colA + 16] += acc1[r];
      }
    }
    __syncthreads();
    float gi = gbuf[tb][tj]      + blds[tj];
    float gf = gbuf[tb][8 + tj]  + blds[8 + tj];
    float gg = gbuf[tb][16 + tj] + blds[16 + tj];
    float go = gbuf[tb][24 + tj] + blds[24 + tj];
    gi = 1.f / (1.f + __expf(-gi));
    gf = 1.f / (1.f + __expf(-gf));
    go = 1.f / (1.f + __expf(-go));
    float e2 = __expf(2.f * fminf(15.f, fmaxf(-15.f, gg)));
    gg = (e2 - 1.f) / (e2 + 1.f);
    c_state = gf * c_state + gi * gg;
    float e2c = __expf(2.f * fminf(15.f, fmaxf(-15.f, c_state)));
    float th = (e2c - 1.f) / (e2c + 1.f);
    float hval = go * th;
    unsigned hu = (unsigned)f2bf(hval);
    unsigned nbv = (unsigned)__shfl_xor((int)hu, 1);
    if ((tj & 1) == 0) {
      unsigned packed = hu | (nbv << 16);
      unsigned* dst = (unsigned*)(hout + (size_t)tb * HH + j0 + tj);
      st_rlx(dst, packed);
    }
    if (wf) h1f[(size_t)tb * HH + j0 + tj] = hval;
  };

  if (!isL1) {
    // ================= layer 0: produces h0 ring, own 128-barrier =================
    for (int t = 0; t < TT; ++t) {
      if (t >= 3) {                      // ring flow control: slot t%3 free?
        if (threadIdx.x == 0)
          while (ld_rlx(relB) < (unsigned)(t - 2)) __builtin_amdgcn_s_sleep(2);
        __syncthreads();
      }
      f32x4 acc0 = {0,0,0,0}, acc1 = {0,0,0,0};
      if (XBF) {
        const u16* xr = xb + (size_t)t * II + (size_t)row_a * ((size_t)TT * II);
#pragma unroll
        for (int ks = ks_begin; ks < r1e; ++ks) {
          int kk = (ks << 5) + koff;
          short8 av = *(const short8*)(xr + kk);
          unsigned o = (unsigned)(kk * 2) ^ mask;
          short8 bv0 = *(const short8*)(wch + (nb0 + o));
          short8 bv1 = *(const short8*)(wch + (nb1 + o));
          acc0 = __builtin_amdgcn_mfma_f32_16x16x32_bf16(av, bv0, acc0, 0, 0, 0);
          acc1 = __builtin_amdgcn_mfma_f32_16x16x32_bf16(av, bv1, acc1, 0, 0, 0);
        }
      } else {
        const float* xr = x + (size_t)t * II + (size_t)row_a * ((size_t)TT * II);
#pragma unroll
        for (int ks = ks_begin; ks < r1e; ++ks) {
          int kk = (ks << 5) + koff;
          short8 av = cvt8(*(const f32x4*)(xr + kk), *(const f32x4*)(xr + kk + 4));
          unsigned o = (unsigned)(kk * 2) ^ mask;
          short8 bv0 = *(const short8*)(wch + (nb0 + o));
          short8 bv1 = *(const short8*)(wch + (nb1 + o));
          acc0 = __builtin_amdgcn_mfma_f32_16x16x32_bf16(av, bv0, acc0, 0, 0, 0);
          acc1 = __builtin_amdgcn_mfma_f32_16x16x32_bf16(av, bv1, acc1, 0, 0, 0);
        }
      }
      // recurrent: h0(t-1) = ring slot (t-1) mod 3
      kloop_h(ring + (size_t)((t + 2) % 3) * HBUF + (size_t)row_a * HH, KX,
              r2b, ks_end, acc0, acc1);
      step_tail(acc0, acc1, ring + (size_t)(t % 3) * HBUF, false);
      // barrier-A (128 L0 blocks); release doubles as producer flag for L1
      __syncthreads();
      if (threadIdx.x == 0) {
        unsigned old = atomicAdd(arrA, 1u);
        if (old == (unsigned)(128 * (t + 1) - 1)) st_rlx(relA, (unsigned)(t + 1));
        else if (t < TT - 1)
          while (ld_rlx(relA) < (unsigned)(t + 1)) __builtin_amdgcn_s_sleep(2);
      }
      __syncthreads();
    }
  } else {
    // ================= layer 1: consumes h0 ring, own 128-barrier =================
    for (int t = 0; t < TT; ++t) {
      if (threadIdx.x == 0)              // producer flag: h0(t) globally visible?
        while (ld_rlx(relA) < (unsigned)(t + 1)) __builtin_amdgcn_s_sleep(2);
      __syncthreads();
      f32x4 acc0 = {0,0,0,0}, acc1 = {0,0,0,0};
      // input: h0(t) = ring slot t%3
      kloop_h(ring + (size_t)(t % 3) * HBUF + (size_t)row_a * HH, 0,
              ks_begin, r1e, acc0, acc1);
      // recurrent: h1(t-1) = slot (t-1)&1
      kloop_h(h1buf + (size_t)((t + 1) & 1) * HBUF + (size_t)row_a * HH, KX,
              r2b, ks_end, acc0, acc1);
      step_tail(acc0, acc1, h1buf + (size_t)(t & 1) * HBUF, t == TT - 1);
      if (t < TT - 1) {                  // barrier-B; release doubles as consumer flag
        __syncthreads();
        if (threadIdx.x == 0) {
          unsigned old = atomicAdd(arrB, 1u);
          if (old == (unsigned)(128 * (t + 1) - 1)) st_rlx(relB, (unsigned)(t + 1));
          else
            while (ld_rlx(relB) < (unsigned)(t + 1)) __builtin_amdgcn_s_sleep(2);
        }
        __syncthreads();
      }
    }
  }
}

// ---- barrier ablation probes: 2048 iterations of the exact barrier pattern ----
template<int NB>
__global__ void bar_probe(unsigned* __restrict__ arr, unsigned* __restrict__ rel) {
  for (int s = 1; s <= 2048; ++s) {
    __syncthreads();
    if (threadIdx.x == 0) {
      unsigned old = atomicAdd(arr, 1u);
      if (old == (unsigned)(NB * s - 1)) st_rlx(rel, (unsigned)s);
      else
        while (ld_rlx(rel) < (unsigned)s) __builtin_amdgcn_s_sleep(2);
    }
    __syncthreads();
  }
}

// out[b][c] = sum_k h1f[b][k] * Wd[c][k] + bd[c]   (all f32)
__global__ void dense_out(const float* __restrict__ h1, const float* __restrict__ Wd,
                          const float* __restrict__ bd, float* __restrict__ out)
{
  const int b  = threadIdx.x & 63;       // batch
  const int cl = threadIdx.x >> 6;
  const int cc = blockIdx.x * 4 + cl;    // class (250*4 = 1000)
  float acc = 0.f;
  const float* hrow = h1 + (size_t)b * HH;
  const float* wrow = Wd + (size_t)cc * HH;
#pragma unroll 8
  for (int k = 0; k < HH; k += 4) {
    f32x4 hv = *(const f32x4*)(hrow + k);
    f32x4 wv = *(const f32x4*)(wrow + k);
    acc += hv[0] * wv[0] + hv[1] * wv[1] + hv[2] * wv[2] + hv[3] * wv[3];
  }
  out[(size_t)b * NCLS + cc] = acc + bd[cc];
}

extern "C" void kernel_launch(void* const* d_in, const int* in_sizes, int n_in,
                              void* d_out, int out_size, void* d_ws, size_t ws_size,
                              hipStream_t stream)
{
  (void)in_sizes; (void)n_in; (void)out_size;
  const float* x    = (const float*)d_in[0];
  const float* Wih0 = (const float*)d_in[1];
  const float* Whh0 = (const float*)d_in[2];
  const float* bih0 = (const float*)d_in[3];
  const float* bhh0 = (const float*)d_in[4];
  const float* Wih1 = (const float*)d_in[5];
  const float* Whh1 = (const float*)d_in[6];
  const float* bih1 = (const float*)d_in[7];
  const float* bhh1 = (const float*)d_in[8];
  const float* Wd   = (const float*)d_in[9];
  const float* bd   = (const float*)d_in[10];

  unsigned* bar = (unsigned*)d_ws;                       // 4 KB barrier/flag words
  float* h1f  = (float*)((char*)d_ws + 4096);            // 256 KB
  u16* h1buf  = (u16*)((char*)d_ws + 272 * 1024);        // 2 x 128 KB
  u16* ring   = (u16*)((char*)d_ws + 528 * 1024);        // 3 x 128 KB
  u16* xb     = (u16*)((char*)d_ws + (1u << 20));        // 33.6 MB (tier A)

  const size_t needA = (1u << 20) + (size_t)BB * TT * II * 2;
  const bool tierA = (ws_size >= needA);

  // zero bars + h buffers every launch (graph-replay deterministic)
  hipMemsetAsync(d_ws, 0, 912 * 1024, stream);

  if (tierA) {
    hipLaunchKernelGGL(cvt_x, dim3(2048), dim3(256), 0, stream,
                       x, xb, (int)((size_t)BB * TT * II / 8));
    hipLaunchKernelGGL((lstm2_fused<true>), dim3(NBLK), dim3(BDIM), 0, stream,
                       x, xb, Wih0, Whh0, bih0, bhh0, Wih1, Whh1, bih1, bhh1,
                       ring, h1buf, h1f, bar);
  } else {
    hipLaunchKernelGGL((lstm2_fused<false>), dim3(NBLK), dim3(BDIM), 0, stream,
                       x, xb, Wih0, Whh0, bih0, bhh0, Wih1, Whh1, bih1, bhh1,
                       ring, h1buf, h1f, bar);
  }
  hipLaunchKernelGGL(dense_out, dim3(250), dim3(256), 0, stream, h1f, Wd, bd,
                     (float*)d_out);

  // barrier cost probes (diagnostic; separate counter lines, zeroed above)
  hipLaunchKernelGGL((bar_probe<256>), dim3(256), dim3(512), 0, stream,
                     bar + 512, bar + 576);
  hipLaunchKernelGGL((bar_probe<128>), dim3(128), dim3(512), 0, stream,
                     bar + 768, bar + 832);
}

// Round 7
// 5418.495 us; speedup vs baseline: 3.8941x; 3.8941x over previous
//
#include <hip/hip_runtime.h>

typedef short short8 __attribute__((ext_vector_type(8)));
typedef float f32x4 __attribute__((ext_vector_type(4)));
typedef int i32x4 __attribute__((ext_vector_type(4)));
typedef unsigned short u16;
typedef unsigned long long u64;

#define NBLK 256
#define BDIM 512
#define BB 64
#define TT 512
#define II 512
#define HH 1024
#define NCLS 1000
#define HBUF (BB*HH)

__device__ __forceinline__ u16 f2bf(float f) {
  union { float f; unsigned u; } v; v.f = f;
  unsigned u = v.u;
  u += 0x7fffu + ((u >> 16) & 1u);   // RNE
  return (u16)(u >> 16);
}

__device__ __forceinline__ short8 cvt8(f32x4 a, f32x4 b) {
  short8 v;
  v[0] = (short)f2bf(a[0]); v[1] = (short)f2bf(a[1]);
  v[2] = (short)f2bf(a[2]); v[3] = (short)f2bf(a[3]);
  v[4] = (short)f2bf(b[0]); v[5] = (short)f2bf(b[1]);
  v[6] = (short)f2bf(b[2]); v[7] = (short)f2bf(b[3]);
  return v;
}

__device__ __forceinline__ unsigned ld_rlx(const unsigned* p) {
  return __hip_atomic_load(p, __ATOMIC_RELAXED, __HIP_MEMORY_SCOPE_AGENT);
}
__device__ __forceinline__ void st_rlx(unsigned* p, unsigned v) {
  __hip_atomic_store(p, v, __ATOMIC_RELAXED, __HIP_MEMORY_SCOPE_AGENT);
}

// x f32 -> bf16 pre-pass (tier A)
__global__ void cvt_x(const float* __restrict__ x, u16* __restrict__ xb, int n8) {
  int i = blockIdx.x * blockDim.x + threadIdx.x;
  const int stride = gridDim.x * blockDim.x;
  for (; i < n8; i += stride) {
    f32x4 a = ((const f32x4*)x)[2 * i];
    f32x4 b = ((const f32x4*)x)[2 * i + 1];
    ((short8*)xb)[i] = cvt8(a, b);
  }
}

// Decoupled persistent 2-layer LSTM. Blocks [0,128)=L0, [128,256)=L1.
// h A-fragments are loaded with inline-asm global_load_dwordx4 sc0 sc1
// (device-coherent at LLC, NON-atomic) in batches of 8 fragments so the
// LLC latency is paid ~4x per wave-section instead of 32x (LLVM refuses to
// batch atomic loads). s_waitcnt vmcnt(0) + sched_barrier(0) fences each batch.
template<bool XBF>
__global__ __launch_bounds__(BDIM, 2) void lstm2_fused(
    const float* __restrict__ x, const u16* __restrict__ xb,
    const float* __restrict__ Wih0, const float* __restrict__ Whh0,
    const float* __restrict__ bih0, const float* __restrict__ bhh0,
    const float* __restrict__ Wih1, const float* __restrict__ Whh1,
    const float* __restrict__ bih1, const float* __restrict__ bhh1,
    u16* __restrict__ ring,          // 3 x [64][1024] bf16 (h0)
    u16* __restrict__ h1buf,         // 2 x [64][1024] bf16 (h1)
    float* __restrict__ h1f,
    unsigned* __restrict__ bar)
{
  __shared__ u16 wlds[32 * 2048];        // 128 KB (L1 row = 2048 elems; L0 uses 1536)
  __shared__ float gbuf[64][33];         // 8.4 KB gate staging (padded)
  __shared__ float blds[32];             // fused biases

  const bool isL1 = (blockIdx.x >= 128);
  const int wgl = isL1 ? (int)blockIdx.x - 128 : (int)blockIdx.x;
  const int j0 = wgl * 8;                // first hidden unit owned
  const int KX = isL1 ? HH : II;         // input-section K
  const int RL = KX + HH;                // total K per row: 2048 / 1536
  const int ROWB = RL * 2;               // row bytes in LDS (bf16)
  const float* Wih = isL1 ? Wih1 : Wih0;
  const float* Whh = isL1 ? Whh1 : Whh0;

  // ---- stage weights into LDS (f32 -> bf16), swizzle byte ^= (row&7)<<4 ----
  {
    const int cpr = RL / 8;
    for (int idx = threadIdx.x; idx < 32 * cpr; idx += BDIM) {
      int n = idx / cpr, cb = idx - n * cpr;
      int r = ((n >> 3) << 10) + j0 + (n & 7);   // global gate row: gate*1024 + j
      int k = cb * 8;
      const float* src = (k < KX) ? (Wih + (size_t)r * KX + k)
                                  : (Whh + (size_t)r * HH + (k - KX));
      f32x4 a = *(const f32x4*)src;
      f32x4 b = *(const f32x4*)(src + 4);
      short8 v = cvt8(a, b);
      unsigned byte = (unsigned)(n * ROWB + k * 2) ^ ((unsigned)(n & 7) << 4);
      *(short8*)((char*)wlds + byte) = v;
    }
    if (threadIdx.x < 32) {
      int n = threadIdx.x;
      int r = ((n >> 3) << 10) + j0 + (n & 7);
      blds[n] = (isL1 ? bih1[r] : bih0[r]) + (isL1 ? bhh1[r] : bhh0[r]);
    }
  }
  __syncthreads();

  const int lane = threadIdx.x & 63;
  const int wid = threadIdx.x >> 6;      // 8 waves
  const int mt = wid & 3, kg = wid >> 2; // 4 M-tiles x 2 K-halves
  const int m0 = mt << 4;
  const int row_a = m0 + (lane & 15);    // batch row for A fragments
  const int koff = (lane >> 4) << 3;     // k sub-offset per A/B layout
  const unsigned mask = (unsigned)(lane & 7) << 4;
  const unsigned nb0 = (unsigned)((lane & 15) * ROWB);
  const unsigned nb1 = nb0 + (unsigned)(16 * ROWB);
  const char* wch = (const char*)wlds;

  const int tb = threadIdx.x >> 3, tj = threadIdx.x & 7;  // update-phase (batch, unit)

  const int nsteps = RL >> 5;            // 48 / 64 k-steps of 32
  const int half = nsteps >> 1;
  const int ks_begin = kg * half, ks_end = ks_begin + half;
  const int bstep = KX >> 5;             // input-region / recurrent-region boundary
  const int r1e = (ks_end < bstep) ? ks_end : bstep;
  const int r2b = (ks_begin > bstep) ? ks_begin : bstep;

  unsigned* const arrA = bar;           // L0 arrive
  unsigned* const relA = bar + 64;      // L0 release / producer flag
  unsigned* const arrB = bar + 256;     // L1 arrive
  unsigned* const relB = bar + 320;     // L1 release / consumer flag

  float c_state = 0.f;

  // Coherent-h K-loop: batches of 8 fragments (8x global_load_dwordx4 sc0 sc1
  // in flight), one vmcnt(0), then 8x {2 ds_read_b128 + 2 MFMA}.
  // All section lengths (8/16/24/32) are multiples of 8.
  auto kloop_h = [&](const u16* base, int kadj, int ks0, int ks1,
                     f32x4& A0, f32x4& A1) {
    for (int c = ks0; c < ks1; c += 8) {
      i32x4 av[8];
#pragma unroll
      for (int i = 0; i < 8; ++i) {
        const u16* p = base + (((c + i) << 5) + koff - kadj);
        asm volatile("global_load_dwordx4 %0, %1, off sc0 sc1"
                     : "=v"(av[i]) : "v"(p));
      }
      asm volatile("s_waitcnt vmcnt(0)" ::: "memory");
      __builtin_amdgcn_sched_barrier(0);
#pragma unroll
      for (int i = 0; i < 8; ++i) {
        int kk = ((c + i) << 5) + koff;
        unsigned o = (unsigned)(kk * 2) ^ mask;
        short8 bv0 = *(const short8*)(wch + (nb0 + o));
        short8 bv1 = *(const short8*)(wch + (nb1 + o));
        union { i32x4 q; short8 s; } u; u.q = av[i];
        A0 = __builtin_amdgcn_mfma_f32_16x16x32_bf16(u.s, bv0, A0, 0, 0, 0);
        A1 = __builtin_amdgcn_mfma_f32_16x16x32_bf16(u.s, bv1, A1, 0, 0, 0);
      }
    }
  };

  // partial-combine + nonlinearity + state update + packed coherent h store
  auto step_tail = [&](f32x4 acc0, f32x4 acc1, u16* hout, bool wf) {
    const int colA = lane & 15;
    const int rowD = m0 + ((lane >> 4) << 2);
    if (kg == 1) {
#pragma unroll
      for (int r = 0; r < 4; ++r) {
        gbuf[rowD + r][colA] = acc0[r];
        gbuf[rowD + r][colA + 16] = acc1[r];
      }
    }
    __syncthreads();
    if (kg == 0) {
#pragma unroll
      for (int r = 0; r < 4; ++r) {
        gbuf[rowD + r][colA] += acc0[r];
        gbuf[rowD + r][colA + 16] += acc1[r];
      }
    }
    __syncthreads();
    float gi = gbuf[tb][tj]      + blds[tj];
    float gf = gbuf[tb][8 + tj]  + blds[8 + tj];
    float gg = gbuf[tb][16 + tj] + blds[16 + tj];
    float go = gbuf[tb][24 + tj] + blds[24 + tj];
    gi = 1.f / (1.f + __expf(-gi));
    gf = 1.f / (1.f + __expf(-gf));
    go = 1.f / (1.f + __expf(-go));
    float e2 = __expf(2.f * fminf(15.f, fmaxf(-15.f, gg)));
    gg = (e2 - 1.f) / (e2 + 1.f);
    c_state = gf * c_state + gi * gg;
    float e2c = __expf(2.f * fminf(15.f, fmaxf(-15.f, c_state)));
    float th = (e2c - 1.f) / (e2c + 1.f);
    float hval = go * th;
    unsigned hu = (unsigned)f2bf(hval);
    unsigned nbv = (unsigned)__shfl_xor((int)hu, 1);
    if ((tj & 1) == 0) {
      unsigned packed = hu | (nbv << 16);
      unsigned* dst = (unsigned*)(hout + (size_t)tb * HH + j0 + tj);
      st_rlx(dst, packed);
    }
    if (wf) h1f[(size_t)tb * HH + j0 + tj] = hval;
  };

  if (!isL1) {
    // ================= layer 0: produces h0 ring, own 128-barrier =================
    for (int t = 0; t < TT; ++t) {
      if (t >= 3) {                      // ring flow control: slot t%3 free?
        if (threadIdx.x == 0)
          while (ld_rlx(relB) < (unsigned)(t - 2)) __builtin_amdgcn_s_sleep(2);
        __syncthreads();
      }
      f32x4 acc0 = {0,0,0,0}, acc1 = {0,0,0,0};
      if (XBF) {
        const u16* xr = xb + (size_t)t * II + (size_t)row_a * ((size_t)TT * II);
#pragma unroll
        for (int ks = ks_begin; ks < r1e; ++ks) {
          int kk = (ks << 5) + koff;
          short8 av = *(const short8*)(xr + kk);
          unsigned o = (unsigned)(kk * 2) ^ mask;
          short8 bv0 = *(const short8*)(wch + (nb0 + o));
          short8 bv1 = *(const short8*)(wch + (nb1 + o));
          acc0 = __builtin_amdgcn_mfma_f32_16x16x32_bf16(av, bv0, acc0, 0, 0, 0);
          acc1 = __builtin_amdgcn_mfma_f32_16x16x32_bf16(av, bv1, acc1, 0, 0, 0);
        }
      } else {
        const float* xr = x + (size_t)t * II + (size_t)row_a * ((size_t)TT * II);
#pragma unroll
        for (int ks = ks_begin; ks < r1e; ++ks) {
          int kk = (ks << 5) + koff;
          short8 av = cvt8(*(const f32x4*)(xr + kk), *(const f32x4*)(xr + kk + 4));
          unsigned o = (unsigned)(kk * 2) ^ mask;
          short8 bv0 = *(const short8*)(wch + (nb0 + o));
          short8 bv1 = *(const short8*)(wch + (nb1 + o));
          acc0 = __builtin_amdgcn_mfma_f32_16x16x32_bf16(av, bv0, acc0, 0, 0, 0);
          acc1 = __builtin_amdgcn_mfma_f32_16x16x32_bf16(av, bv1, acc1, 0, 0, 0);
        }
      }
      // recurrent: h0(t-1) = ring slot (t-1) mod 3
      kloop_h(ring + (size_t)((t + 2) % 3) * HBUF + (size_t)row_a * HH, KX,
              r2b, ks_end, acc0, acc1);
      step_tail(acc0, acc1, ring + (size_t)(t % 3) * HBUF, false);
      // barrier-A (128 L0 blocks); release doubles as producer flag for L1
      __syncthreads();
      if (threadIdx.x == 0) {
        unsigned old = atomicAdd(arrA, 1u);
        if (old == (unsigned)(128 * (t + 1) - 1)) st_rlx(relA, (unsigned)(t + 1));
        else if (t < TT - 1)
          while (ld_rlx(relA) < (unsigned)(t + 1)) __builtin_amdgcn_s_sleep(2);
      }
      __syncthreads();
    }
  } else {
    // ================= layer 1: consumes h0 ring, own 128-barrier =================
    for (int t = 0; t < TT; ++t) {
      if (threadIdx.x == 0)              // producer flag: h0(t) globally visible?
        while (ld_rlx(relA) < (unsigned)(t + 1)) __builtin_amdgcn_s_sleep(2);
      __syncthreads();
      f32x4 acc0 = {0,0,0,0}, acc1 = {0,0,0,0};
      // input: h0(t) = ring slot t%3
      kloop_h(ring + (size_t)(t % 3) * HBUF + (size_t)row_a * HH, 0,
              ks_begin, r1e, acc0, acc1);
      // recurrent: h1(t-1) = slot (t-1)&1
      kloop_h(h1buf + (size_t)((t + 1) & 1) * HBUF + (size_t)row_a * HH, KX,
              r2b, ks_end, acc0, acc1);
      step_tail(acc0, acc1, h1buf + (size_t)(t & 1) * HBUF, t == TT - 1);
      if (t < TT - 1) {                  // barrier-B; release doubles as consumer flag
        __syncthreads();
        if (threadIdx.x == 0) {
          unsigned old = atomicAdd(arrB, 1u);
          if (old == (unsigned)(128 * (t + 1) - 1)) st_rlx(relB, (unsigned)(t + 1));
          else
            while (ld_rlx(relB) < (unsigned)(t + 1)) __builtin_amdgcn_s_sleep(2);
        }
        __syncthreads();
      }
    }
  }
}

// out[b][c] = sum_k h1f[b][k] * Wd[c][k] + bd[c]   (all f32)
__global__ void dense_out(const float* __restrict__ h1, const float* __restrict__ Wd,
                          const float* __restrict__ bd, float* __restrict__ out)
{
  const int b  = threadIdx.x & 63;       // batch
  const int cl = threadIdx.x >> 6;
  const int cc = blockIdx.x * 4 + cl;    // class (250*4 = 1000)
  float acc = 0.f;
  const float* hrow = h1 + (size_t)b * HH;
  const float* wrow = Wd + (size_t)cc * HH;
#pragma unroll 8
  for (int k = 0; k < HH; k += 4) {
    f32x4 hv = *(const f32x4*)(hrow + k);
    f32x4 wv = *(const f32x4*)(wrow + k);
    acc += hv[0] * wv[0] + hv[1] * wv[1] + hv[2] * wv[2] + hv[3] * wv[3];
  }
  out[(size_t)b * NCLS + cc] = acc + bd[cc];
}

extern "C" void kernel_launch(void* const* d_in, const int* in_sizes, int n_in,
                              void* d_out, int out_size, void* d_ws, size_t ws_size,
                              hipStream_t stream)
{
  (void)in_sizes; (void)n_in; (void)out_size;
  const float* x    = (const float*)d_in[0];
  const float* Wih0 = (const float*)d_in[1];
  const float* Whh0 = (const float*)d_in[2];
  const float* bih0 = (const float*)d_in[3];
  const float* bhh0 = (const float*)d_in[4];
  const float* Wih1 = (const float*)d_in[5];
  const float* Whh1 = (const float*)d_in[6];
  const float* bih1 = (const float*)d_in[7];
  const float* bhh1 = (const float*)d_in[8];
  const float* Wd   = (const float*)d_in[9];
  const float* bd   = (const float*)d_in[10];

  unsigned* bar = (unsigned*)d_ws;                       // 4 KB barrier/flag words
  float* h1f  = (float*)((char*)d_ws + 4096);            // 256 KB
  u16* h1buf  = (u16*)((char*)d_ws + 272 * 1024);        // 2 x 128 KB
  u16* ring   = (u16*)((char*)d_ws + 528 * 1024);        // 3 x 128 KB
  u16* xb     = (u16*)((char*)d_ws + (1u << 20));        // 33.6 MB (tier A)

  const size_t needA = (1u << 20) + (size_t)BB * TT * II * 2;
  const bool tierA = (ws_size >= needA);

  // zero bars + h buffers every launch (graph-replay deterministic)
  hipMemsetAsync(d_ws, 0, 912 * 1024, stream);

  if (tierA) {
    hipLaunchKernelGGL(cvt_x, dim3(2048), dim3(256), 0, stream,
                       x, xb, (int)((size_t)BB * TT * II / 8));
    hipLaunchKernelGGL((lstm2_fused<true>), dim3(NBLK), dim3(BDIM), 0, stream,
                       x, xb, Wih0, Whh0, bih0, bhh0, Wih1, Whh1, bih1, bhh1,
                       ring, h1buf, h1f, bar);
  } else {
    hipLaunchKernelGGL((lstm2_fused<false>), dim3(NBLK), dim3(BDIM), 0, stream,
                       x, xb, Wih0, Whh0, bih0, bhh0, Wih1, Whh1, bih1, bhh1,
                       ring, h1buf, h1f, bar);
  }
  hipLaunchKernelGGL(dense_out, dim3(250), dim3(256), 0, stream, h1f, Wd, bd,
                     (float*)d_out);
}